// Round 16
// baseline (57.380 us; speedup 1.0000x reference)
//
#include <hip/hip_runtime.h>
#include <hip/hip_bf16.h>

#define B_    4096
#define D_    512         // elements = bytes per row (i8)
#define TB_   8192        // 2B rows
#define BM    128
#define BK    128         // 128 B per row per K-tile (0-conflict geometry)
#define NK    4           // D_/BK
#define NTILE 64          // TB_/BM
#define NTRI  2080        // NTILE*(NTILE+1)/2 = 8*260 (XCD-bijective)
#define INV_T 14.285714285714286f   // 1/0.07
#define SCL   (INV_T / 16129.0f)    // 1/(0.07*127*127)
#define SCL2  (SCL * 1.4426950408889634f)   // SCL*log2(e): v_exp_f32 is 2^x

typedef __attribute__((ext_vector_type(4))) int v4i;

#define GLOAD_LDS16(gp, lp)                                                        \
  __builtin_amdgcn_global_load_lds((const __attribute__((address_space(1))) void*)(gp), \
                                   (__attribute__((address_space(3))) void*)(lp),  \
                                   16, 0, 0)

// ---------------------------------------------------------------------------
// Kernel 1: concat + quantize fp32 -> int8 (E8[8192][512], q = rn(127 x)).
// ---------------------------------------------------------------------------
__global__ void ntx_prep(const float* __restrict__ a, const float* __restrict__ b,
                         char* __restrict__ E8) {
  int t = blockIdx.x * blockDim.x + threadIdx.x;      // 0..262143
  int i = t * 16;
  const float* src = (i < B_ * D_) ? (a + i) : (b + (i - B_ * D_));
  v4i o;
#pragma unroll
  for (int g = 0; g < 4; ++g) {
    float4 v = ((const float4*)src)[g];
    int q0 = __float2int_rn(v.x * 127.0f) & 255;
    int q1 = __float2int_rn(v.y * 127.0f) & 255;
    int q2 = __float2int_rn(v.z * 127.0f) & 255;
    int q3 = __float2int_rn(v.w * 127.0f) & 255;
    o[g] = q0 | (q1 << 8) | (q2 << 16) | (q3 << 24);
  }
  ((v4i*)E8)[t] = o;
}

// ---------------------------------------------------------------------------
// Kernel 2: R14's 16-wave 128x128 i8 structure (best occupancy: 67%) +
// (1) double-buffered LDS with counted vmcnt(2): each thread has EXACTLY
//     2 staging loads/tile, so after issuing tile kt+1, vmcnt(2) completes
//     precisely tile kt; kt+1's loads stay in flight across both barriers.
//     Raw s_barrier + empty asm memory-clobber (compiler fence, 0 instr).
//     WAR safe: reads' MFMA consumers precede the end barrier; buffers
//     alternate by parity (stage at iter kt writes buf[(kt+1)&1], which was
//     last read at iter kt-1, separated by iter kt-1's end barrier).
// (2) inline v_exp_f32 (2^x) with prefolded SCL2 — no libm range checks.
// (3) __launch_bounds__(1024, 8): forces <=64 unified regs (R14 used 44)
//     -> 2 blocks/CU co-resident (LDS 64 KB fits 2).
// Epilogue (R14-verified): per-wave partials -> cross-wave LDS reduce ->
// single-writer P[ti][tj][128]. Triangular; mirror col-sums; pos tj==ti+32.
// ---------------------------------------------------------------------------
__global__ __launch_bounds__(1024, 8)
void ntx_sim(const char* __restrict__ E8, float* __restrict__ P,
             float* __restrict__ pos) {
  __shared__ __align__(16) char As[2][BM * BK];   // 2 x 16 KB
  __shared__ __align__(16) char Bs[2][BM * BK];   // 2 x 16 KB

  // XCD-contiguous bijective swizzle (2080 = 8*260)
  const int bid = blockIdx.x;
  const int t   = (bid & 7) * (NTRI / 8) + (bid >> 3);
  // decode triangular index t -> (ti, tj), ti<=tj
  int ti = (int)((129.0f - sqrtf(16641.0f - 8.0f * (float)t)) * 0.5f);
  while (ti * (129 - ti) / 2 > t) --ti;
  while ((ti + 1) * (128 - ti) / 2 <= t) ++ti;
  const int tj = ti + (t - ti * (129 - ti) / 2);
  const int rowTile = ti * BM, colTile = tj * BM;
  const bool diag = (ti == tj);
  const bool posT = (tj == ti + B_ / BM);   // holds s[r][r+B] on local diag

  const int tid = threadIdx.x, lane = tid & 63, wave = tid >> 6;
  const int wr = wave >> 2;          // 0..3: 32-row band
  const int wc = wave & 3;           // 0..3: 32-col band
  const int llo = lane & 15, lhi = lane >> 4;

  // staging: tile = 128 rows x 8 chunks(16B) = 1024 chunks; 1/thread/matrix.
  // source pre-swizzled (chunk ^= row&7), LDS linear (both-sides rule #21)
  const int ch = tid, srow = ch >> 3;
  const int sc = ((ch & 7) ^ (srow & 7)) << 4;
  const unsigned offA  = (unsigned)(rowTile + srow) * D_ + sc;
  const unsigned offB  = (unsigned)(colTile + srow) * D_ + sc;
  const unsigned ldsOf = (unsigned)ch * 16;

  // fragment byte-offsets (same involution on read); 16 B per lane per ks
  unsigned fA[2][2], fB[2][2];
#pragma unroll
  for (int ks = 0; ks < 2; ++ks)
#pragma unroll
    for (int m = 0; m < 2; ++m) {
      int chc = ks * 4 + lhi;
      int ra  = wr * 32 + m * 16 + llo;
      fA[ks][m] = (unsigned)(ra * BK + (((unsigned)chc ^ (ra & 7)) << 4));
      int rb  = wc * 32 + m * 16 + llo;
      fB[ks][m] = (unsigned)(rb * BK + (((unsigned)chc ^ (rb & 7)) << 4));
    }

  v4i acc[2][2] = {};

  // prologue: stage tile 0 -> buf 0 (2 loads in flight)
  GLOAD_LDS16(E8 + offA, &As[0][ldsOf]);
  GLOAD_LDS16(E8 + offB, &Bs[0][ldsOf]);

#pragma unroll
  for (int kt = 0; kt < NK; ++kt) {
    const int c = kt & 1;
    // issue next tile's stage FIRST (its latency hides under MFMA below)
    if (kt + 1 < NK) {
      const unsigned kb = (unsigned)(kt + 1) * BK;
      GLOAD_LDS16(E8 + offA + kb, &As[c ^ 1][ldsOf]);
      GLOAD_LDS16(E8 + offB + kb, &Bs[c ^ 1][ldsOf]);
      asm volatile("s_waitcnt vmcnt(2)" ::: "memory");  // tile kt landed; 2 in flight
    } else {
      asm volatile("s_waitcnt vmcnt(0)" ::: "memory");
    }
    __builtin_amdgcn_s_barrier();          // all waves' tile-kt data visible
    asm volatile("" ::: "memory");         // compiler fence: no read hoisting
#pragma unroll
    for (int ks = 0; ks < 2; ++ks) {
      v4i af[2], bf[2];
#pragma unroll
      for (int m = 0; m < 2; ++m) {
        af[m] = *(const v4i*)&As[c][fA[ks][m]];
        bf[m] = *(const v4i*)&Bs[c][fB[ks][m]];
      }
#pragma unroll
      for (int m = 0; m < 2; ++m)
#pragma unroll
        for (int n = 0; n < 2; ++n)
          acc[m][n] = __builtin_amdgcn_mfma_i32_16x16x64_i8(af[m], bf[n],
                                                            acc[m][n], 0, 0, 0);
    }
    if (kt + 1 < NK) {
      __builtin_amdgcn_s_barrier();        // reads of buf c done -> restage ok
      asm volatile("" ::: "memory");
    }
  }
  __syncthreads();   // full fence before LDS reuse by epilogue

  // --- epilogue: v_exp_f32, per-wave partials, cross-wave LDS reduce ---
  // C/D layout: col = lane&15, row = (lane>>4)*4 + reg
  float* Rbuf = (float*)&As[0][0];   // [4 wc][128 rows] = 2 KB (LDS reuse)
  float* Cbuf = (float*)&Bs[0][0];   // [4 wr][128 cols] = 2 KB
  float cs[2] = {0.f, 0.f};
#pragma unroll
  for (int m = 0; m < 2; ++m) {
    float rs[4] = {0.f, 0.f, 0.f, 0.f};
#pragma unroll
    for (int n = 0; n < 2; ++n) {
      int gc = colTile + wc * 32 + n * 16 + llo;
#pragma unroll
      for (int jj = 0; jj < 4; ++jj) {
        int gr = rowTile + wr * 32 + m * 16 + lhi * 4 + jj;
        float si = (float)acc[m][n][jj];
        if (posT && gc - gr == B_) pos[gr] = si * SCL;   // unique writer
        float x = si * SCL2;
        float e;
        asm("v_exp_f32 %0, %1" : "=v"(e) : "v"(x));      // 2^x, 1 instr
        e = (diag && gr == gc) ? 0.0f : e;
        rs[jj] += e;
        cs[n]  += e;
      }
    }
#pragma unroll
    for (int jj = 0; jj < 4; ++jj) {
      float v = rs[jj];
      v += __shfl_xor(v, 1);
      v += __shfl_xor(v, 2);
      v += __shfl_xor(v, 4);
      v += __shfl_xor(v, 8);
      if (llo == 0) Rbuf[wc * 128 + wr * 32 + m * 16 + lhi * 4 + jj] = v;
    }
  }
#pragma unroll
  for (int n = 0; n < 2; ++n) {
    float v = cs[n];
    v += __shfl_xor(v, 16);
    v += __shfl_xor(v, 32);
    if (lhi == 0) Cbuf[wr * 128 + wc * 32 + n * 16 + llo] = v;
  }
  __syncthreads();
  if (tid < 128) {
    float v = Rbuf[tid] + Rbuf[128 + tid] + Rbuf[256 + tid] + Rbuf[384 + tid];
    P[((size_t)ti * NTILE + tj) * BM + tid] = v;          // one writer/slot
  } else if (tid < 256 && !diag) {
    int c = tid - 128;
    float v = Cbuf[c] + Cbuf[128 + c] + Cbuf[256 + c] + Cbuf[384 + c];
    P[((size_t)tj * NTILE + ti) * BM + c] = v;            // mirror slot
  }
}

// ---------------------------------------------------------------------------
// Kernel 3: gather L[r] = sum_j P[ti][j][rloc]; nll = log(L) - pos;
// per-block partial -> par[32].
// ---------------------------------------------------------------------------
__global__ void ntx_fin1(const float* __restrict__ P, const float* __restrict__ pos,
                         float* __restrict__ par) {
  int r = blockIdx.x * 256 + threadIdx.x;     // 32 blocks x 256 rows
  int ti = r >> 7, rloc = r & 127;
  const float* base = P + (size_t)ti * NTILE * BM + rloc;
  float s = 0.f;
#pragma unroll 16
  for (int j = 0; j < NTILE; ++j) s += base[j * BM];
  float nll = __logf(s) - pos[r & (B_ - 1)];
  float v = nll;
#pragma unroll
  for (int off = 1; off < 64; off <<= 1) v += __shfl_xor(v, off);
  __shared__ float sm[4];
  if ((threadIdx.x & 63) == 0) sm[threadIdx.x >> 6] = v;
  __syncthreads();
  if (threadIdx.x == 0) par[blockIdx.x] = sm[0] + sm[1] + sm[2] + sm[3];
}

// Kernel 4: fold 32 partials -> mean
__global__ void ntx_fin2(const float* __restrict__ par, float* __restrict__ out) {
  int t = threadIdx.x;                         // 64 threads
  float s = (t < 32) ? par[t] : 0.f;
#pragma unroll
  for (int off = 1; off < 32; off <<= 1) s += __shfl_xor(s, off);
  if (t == 0) out[0] = s * (1.0f / TB_);
}

// ---------------------------------------------------------------------------
extern "C" void kernel_launch(void* const* d_in, const int* in_sizes, int n_in,
                              void* d_out, int out_size, void* d_ws, size_t ws_size,
                              hipStream_t stream) {
  const float* e1 = (const float*)d_in[0];
  const float* e2 = (const float*)d_in[1];
  float* out = (float*)d_out;
  char*  E8  = (char*)d_ws;                                       // 4 MB i8
  float* P   = (float*)((char*)d_ws + (size_t)TB_ * D_);          // 2 MB partials
  float* pos = P + (size_t)NTILE * NTILE * BM;                    // 16 KB
  float* par = pos + B_;                                          // 128 B

  ntx_prep<<<1024, 256, 0, stream>>>(e1, e2, E8);
  ntx_sim<<<NTRI, 1024, 0, stream>>>(E8, P, pos);
  ntx_fin1<<<TB_ / 256, 256, 0, stream>>>(P, pos, par);
  ntx_fin2<<<1, 64, 0, stream>>>(par, out);
}

// Round 17
// 50.081 us; speedup vs baseline: 1.1457x; 1.1457x over previous
//
#include <hip/hip_runtime.h>
#include <hip/hip_bf16.h>

#define B_    4096
#define D_    512         // elements = bytes per row (i8)
#define TB_   8192        // 2B rows
#define BM    128
#define BK    128         // 128 B per row per K-tile (0-conflict geometry)
#define NK    4           // D_/BK
#define NTILE 64          // TB_/BM
#define NTRI  2080        // NTILE*(NTILE+1)/2 = 8*260 (XCD-bijective)
#define INV_T 14.285714285714286f   // 1/0.07
#define SCL   (INV_T / 16129.0f)    // 1/(0.07*127*127)

typedef __attribute__((ext_vector_type(4))) int v4i;

#define GLOAD_LDS16(gp, lp)                                                        \
  __builtin_amdgcn_global_load_lds((const __attribute__((address_space(1))) void*)(gp), \
                                   (__attribute__((address_space(3))) void*)(lp),  \
                                   16, 0, 0)

// ---------------------------------------------------------------------------
// Kernel 1: concat + quantize fp32 -> int8 (E8[8192][512], q = rn(127 x)).
// ---------------------------------------------------------------------------
__global__ void ntx_prep(const float* __restrict__ a, const float* __restrict__ b,
                         char* __restrict__ E8) {
  int t = blockIdx.x * blockDim.x + threadIdx.x;      // 0..262143
  int i = t * 16;
  const float* src = (i < B_ * D_) ? (a + i) : (b + (i - B_ * D_));
  v4i o;
#pragma unroll
  for (int g = 0; g < 4; ++g) {
    float4 v = ((const float4*)src)[g];
    int q0 = __float2int_rn(v.x * 127.0f) & 255;
    int q1 = __float2int_rn(v.y * 127.0f) & 255;
    int q2 = __float2int_rn(v.z * 127.0f) & 255;
    int q3 = __float2int_rn(v.w * 127.0f) & 255;
    o[g] = q0 | (q1 << 8) | (q2 << 16) | (q3 << 24);
  }
  ((v4i*)E8)[t] = o;
}

// ---------------------------------------------------------------------------
// Kernel 2: R13's i8 GEMM (128x128 tile, 4 waves of 64x64, BK=128, simple
// 2-barrier loop, atomic-free P-partial epilogue — best measured) with a
// VGPR DIET to break the 128-unified-reg occupancy boundary (60+64acc=124
// ~> 128 -> 8 waves/CU observed):
//  (a) frag offsets: ra&7 == llo&7 (m*16 = 0 mod 8), so
//      fA[ks][m] = baseA ^ (ks*64) + m*2048  — 16 regs -> 2 scalars + imms.
//  (b) staging offsets: swizzle col invariant in round r, so
//      offA0 + r*16384, ldsOf = tid*16 + r*4096 — 12 regs -> 2.
// Everything else byte-identical to R13 (passed, 50.3 us total).
// ---------------------------------------------------------------------------
__global__ __launch_bounds__(256, 4)
void ntx_sim(const char* __restrict__ E8, float* __restrict__ P,
             float* __restrict__ pos) {
  __shared__ __align__(16) char As[BM * BK];   // 16 KB
  __shared__ __align__(16) char Bs[BM * BK];   // 16 KB

  // XCD-contiguous bijective swizzle (2080 = 8*260)
  const int bid = blockIdx.x;
  const int t   = (bid & 7) * (NTRI / 8) + (bid >> 3);
  // decode triangular index t -> (ti, tj), ti<=tj
  int ti = (int)((129.0f - sqrtf(16641.0f - 8.0f * (float)t)) * 0.5f);
  while (ti * (129 - ti) / 2 > t) --ti;
  while ((ti + 1) * (128 - ti) / 2 <= t) ++ti;
  const int tj = ti + (t - ti * (129 - ti) / 2);
  const int rowTile = ti * BM, colTile = tj * BM;
  const bool diag = (ti == tj);
  const bool posT = (tj == ti + B_ / BM);   // holds s[r][r+B] on local diag

  const int tid = threadIdx.x, lane = tid & 63, wave = tid >> 6;
  const int wr = wave >> 1, wc = wave & 1;
  const int llo = lane & 15, lhi = lane >> 4;

  // --- staging bases (round r adds r*16384 global / r*4096 LDS) ---
  // chunk = tid (+r*256); row = chunk>>3; swizzle col = ((tid&7)^((tid>>3)&7))
  // is invariant in r because r*32 rows == 0 mod 8.
  const int srow = tid >> 3;
  const int ssc  = ((tid & 7) ^ (srow & 7)) << 4;
  const unsigned offA0  = (unsigned)(rowTile + srow) * D_ + ssc;
  const unsigned offB0  = (unsigned)(colTile + srow) * D_ + ssc;
  const unsigned ldsOf0 = (unsigned)tid * 16;

  // --- fragment bases: fA[ks][m] = baseA ^ (ks*64) + m*2048 ---
  const unsigned baseA = (unsigned)((wr * 64 + llo) * BK + ((lhi ^ (llo & 7)) << 4));
  const unsigned baseB = (unsigned)((wc * 64 + llo) * BK + ((lhi ^ (llo & 7)) << 4));

  v4i acc[4][4] = {};

  for (int kt = 0; kt < NK; ++kt) {
    const unsigned kb = (unsigned)kt * BK;
#pragma unroll
    for (int r = 0; r < 4; ++r) {
      GLOAD_LDS16(E8 + offA0 + r * 16384 + kb, &As[ldsOf0 + r * 4096]);
      GLOAD_LDS16(E8 + offB0 + r * 16384 + kb, &Bs[ldsOf0 + r * 4096]);
    }
    __syncthreads();   // drains vmcnt: tile resident
#pragma unroll
    for (int ks = 0; ks < 2; ++ks) {
      const unsigned bA = baseA ^ (ks * 64);
      const unsigned bB = baseB ^ (ks * 64);
      v4i af[4], bf[4];
#pragma unroll
      for (int m = 0; m < 4; ++m) {
        af[m] = *(const v4i*)&As[bA + m * 2048];
        bf[m] = *(const v4i*)&Bs[bB + m * 2048];
      }
#pragma unroll
      for (int m = 0; m < 4; ++m)
#pragma unroll
        for (int n = 0; n < 4; ++n)
          acc[m][n] = __builtin_amdgcn_mfma_i32_16x16x64_i8(af[m], bf[n],
                                                            acc[m][n], 0, 0, 0);
    }
    __syncthreads();   // protect LDS before next staging
  }

  // --- epilogue (R13-verified): exp, partials, single-writer P stores ---
  // C/D layout: col = lane&15, row = (lane>>4)*4 + reg
  float* __restrict__ Prow = P + ((size_t)ti * 2 * NTILE + (size_t)tj * 2 + wc) * BM;
  float* __restrict__ Pcol = P + ((size_t)tj * 2 * NTILE + (size_t)ti * 2 + wr) * BM;
  float cs[4] = {0.f, 0.f, 0.f, 0.f};
#pragma unroll
  for (int m = 0; m < 4; ++m) {
    float rs[4] = {0.f, 0.f, 0.f, 0.f};
#pragma unroll
    for (int n = 0; n < 4; ++n) {
      int gc = colTile + wc * 64 + n * 16 + llo;
#pragma unroll
      for (int jj = 0; jj < 4; ++jj) {
        int gr = rowTile + wr * 64 + m * 16 + lhi * 4 + jj;
        float s = (float)acc[m][n][jj] * SCL;
        if (posT && gc - gr == B_) pos[gr] = s;   // unique writer
        float e = __expf(s);
        e = (diag && gr == gc) ? 0.0f : e;
        rs[jj] += e;
        cs[n]  += e;
      }
    }
#pragma unroll
    for (int jj = 0; jj < 4; ++jj) {
      float v = rs[jj];
      v += __shfl_xor(v, 1);
      v += __shfl_xor(v, 2);
      v += __shfl_xor(v, 4);
      v += __shfl_xor(v, 8);
      if (llo == 0) Prow[wr * 64 + m * 16 + lhi * 4 + jj] = v;  // slot tj*2+wc
    }
  }
  if (!diag) {
    // column sums = row sums of mirrored tile (j,i)
#pragma unroll
    for (int n = 0; n < 4; ++n) {
      float v = cs[n];
      v += __shfl_xor(v, 16);
      v += __shfl_xor(v, 32);
      if (lhi == 0) Pcol[wc * 64 + n * 16 + llo] = v;           // slot ti*2+wr
    }
  }
}

// ---------------------------------------------------------------------------
// Kernel 3: gather L[r] = sum over 128 slots of P[ti][j2][rloc];
// nll = log(L) - pos; per-block partial -> par[32].
// ---------------------------------------------------------------------------
__global__ void ntx_fin1(const float* __restrict__ P, const float* __restrict__ pos,
                         float* __restrict__ par) {
  int r = blockIdx.x * 256 + threadIdx.x;     // 32 blocks x 256 rows
  int ti = r >> 7, rloc = r & 127;
  const float* base = P + (size_t)ti * 2 * NTILE * BM + rloc;
  float s = 0.f;
#pragma unroll 16
  for (int j = 0; j < 2 * NTILE; ++j) s += base[j * BM];
  float nll = __logf(s) - pos[r & (B_ - 1)];
  float v = nll;
#pragma unroll
  for (int off = 1; off < 64; off <<= 1) v += __shfl_xor(v, off);
  __shared__ float sm[4];
  if ((threadIdx.x & 63) == 0) sm[threadIdx.x >> 6] = v;
  __syncthreads();
  if (threadIdx.x == 0) par[blockIdx.x] = sm[0] + sm[1] + sm[2] + sm[3];
}

// Kernel 4: fold 32 partials -> mean
__global__ void ntx_fin2(const float* __restrict__ par, float* __restrict__ out) {
  int t = threadIdx.x;                         // 64 threads
  float s = (t < 32) ? par[t] : 0.f;
#pragma unroll
  for (int off = 1; off < 32; off <<= 1) s += __shfl_xor(s, off);
  if (t == 0) out[0] = s * (1.0f / TB_);
}

// ---------------------------------------------------------------------------
extern "C" void kernel_launch(void* const* d_in, const int* in_sizes, int n_in,
                              void* d_out, int out_size, void* d_ws, size_t ws_size,
                              hipStream_t stream) {
  const float* e1 = (const float*)d_in[0];
  const float* e2 = (const float*)d_in[1];
  float* out = (float*)d_out;
  char*  E8  = (char*)d_ws;                                       // 4 MB i8
  float* P   = (float*)((char*)d_ws + (size_t)TB_ * D_);          // 4 MB partials
  float* pos = P + (size_t)NTILE * 2 * NTILE * BM;                // 16 KB
  float* par = pos + B_;                                          // 128 B

  ntx_prep<<<1024, 256, 0, stream>>>(e1, e2, E8);
  ntx_sim<<<NTRI, 256, 0, stream>>>(E8, P, pos);
  ntx_fin1<<<TB_ / 256, 256, 0, stream>>>(P, pos, par);
  ntx_fin2<<<1, 64, 0, stream>>>(par, out);
}